// Round 2
// baseline (1477.880 us; speedup 1.0000x reference)
//
#include <hip/hip_runtime.h>
#include <stdint.h>

// Persistent-kernel RNN: 256 wgs (1/CU), W_hh bf16 resident in LDS (16 j-slices),
// batch split 16 ways; h exchanged via MALL with per-group flags.
// R4: h DATA loads are now plain (cacheable in L1/L2); coherence is restored by
// an explicit agent-scope acquire-invalidate (buffer_inv sc1 + sc0) once per wg
// per step, after the flag spin and before the staging loads. Producers still
// release with sc0 sc1 stores + device-scope flags (MALL = point of truth), so
// the first reader per XCD misses to MALL and the other 15 jg peers hit the
// XCD's L2 — cutting the ~16 MB/step MALL read burst ~16x and the h-load
// latency from ~MALL-RTT to ~L2-RTT.
// Staleness safety: ping-pong hbuf means a line is re-read only 2 steps later;
// every wg invalidates every step, and the flag protocol bounds peer skew to
// <2 steps, so any line present in L2 after this step's inv was allocated by a
// same-step peer and is valid. All our global stores are sc0 sc1 (write-through),
// so buffer_inv can never discard dirty data (out store made sc0 sc1 for this).
// R3 lesson (hung): sc0-only cross-wg sync never becomes visible — gfx950 has
// no XCD-local coherence scope; keep flags/stores device-scope.

#define BATCH 512
#define SEQ   256
#define HID   1024
#define CLS   128

#define GB 16          // batch groups
#define GJ 16          // hidden slices
#define BT 32          // batch rows per wg
#define JT 64          // hidden cols per wg
#define KC 256         // k-chunk per stage buffer fill
#define WSTR 1028      // W LDS row stride (halves): 2-way banks, 8B aligned
#define SSTR 260       // stage row stride (halves)
#define HSTR 68        // h-store exchange row stride (halves)
#define SMEM_BYTES ((JT * WSTR + BT * SSTR) * 2)   // 148224 B
#define HBUF_HALVES (BATCH * HID)                  // 1 MB per buffer

typedef __attribute__((ext_vector_type(8))) short  bf16x8;
typedef __attribute__((ext_vector_type(4))) short  s16x4;
typedef __attribute__((ext_vector_type(4))) float  f32x4;
typedef __attribute__((ext_vector_type(4))) int    i32x4;
typedef __attribute__((ext_vector_type(2))) unsigned int u32x2;

__device__ __forceinline__ unsigned short f2bf(float f) {
  unsigned int u = __float_as_uint(f);
  u = (u + 0x7FFFu + ((u >> 16) & 1u)) >> 16;   // RNE
  return (unsigned short)u;
}
__device__ __forceinline__ float b2f(short h) {
  return __uint_as_float(((unsigned int)(unsigned short)h) << 16);
}

// ---- device-coherent (MALL) accesses for the release/acquire protocol ----
__device__ __forceinline__ void store_flag(int* p, int v) {
  asm volatile("global_store_dword %0, %1, off sc0 sc1" :: "v"(p), "v"(v) : "memory");
}
__device__ __forceinline__ int load_flag(const int* p) {
  int v;
  asm volatile("global_load_dword %0, %1, off sc0 sc1\n\t"
               "s_waitcnt vmcnt(0)" : "=v"(v) : "v"(p) : "memory");
  return v;
}
__device__ __forceinline__ void store16(void* p, i32x4 v) {
  asm volatile("global_store_dwordx4 %0, %1, off sc0 sc1" :: "v"(p), "v"(v) : "memory");
}
__device__ __forceinline__ void storef(float* p, float v) {
  // out must not sit dirty in L2 (a slower peer's buffer_inv could discard it)
  asm volatile("global_store_dword %0, %1, off sc0 sc1" :: "v"(p), "v"(v) : "memory");
}
__device__ __forceinline__ void waitcnt0() {
  asm volatile("s_waitcnt vmcnt(0)" ::: "memory");
}
// agent-scope acquire invalidate: L2 (sc1) then L1 (sc0). Completion is drained
// by the compiler's vmcnt(0) before the following s_barrier (__syncthreads).
__device__ __forceinline__ void cache_inv_l1l2() {
  asm volatile("buffer_inv sc1\n\tbuffer_inv sc0" ::: "memory");
}
// raw workgroup barrier: drains LDS ops only — global loads stay in flight
__device__ __forceinline__ void barrier_lgkm() {
  asm volatile("s_waitcnt lgkmcnt(0)\n\ts_barrier" ::: "memory");
}
// issue 4x dwordx4 PLAIN (cacheable) loads (64 B/thread), no wait.
// Valid because cache_inv_l1l2 ran after the flag acquire this step.
__device__ __forceinline__ void issue4(const void* p, i32x4& a, i32x4& b, i32x4& c, i32x4& d) {
  asm volatile(
    "global_load_dwordx4 %0, %4, off\n\t"
    "global_load_dwordx4 %1, %4, off offset:128\n\t"
    "global_load_dwordx4 %2, %4, off offset:256\n\t"
    "global_load_dwordx4 %3, %4, off offset:384"
    : "=&v"(a), "=&v"(b), "=&v"(c), "=&v"(d)
    : "v"(p) : "memory");
}
// counted waits, tying the chunk's registers so LDS writes can't be hoisted
#define DEF_WAIT(NAME, N) \
__device__ __forceinline__ void NAME(i32x4& a, i32x4& b, i32x4& c, i32x4& d) { \
  asm volatile("s_waitcnt vmcnt(" #N ")" : "+v"(a), "+v"(b), "+v"(c), "+v"(d) :: "memory"); \
}
DEF_WAIT(wait_vm12, 12)
DEF_WAIT(wait_vm8, 8)
DEF_WAIT(wait_vm4, 4)
DEF_WAIT(wait_vm0, 0)

__device__ __forceinline__ void wr16(short* p, i32x4 v) {  // 16 B to LDS as 2x b64
  u32x2 lo, hi;
  lo.x = (unsigned)v.x; lo.y = (unsigned)v.y;
  hi.x = (unsigned)v.z; hi.y = (unsigned)v.w;
  *(u32x2*)p = lo;
  *(u32x2*)(p + 4) = hi;
}
__device__ __forceinline__ bf16x8 ld8(const short* p) {    // 8 bf16 from LDS as 2x b64
  union { bf16x8 v8; s16x4 h[2]; } u;
  u.h[0] = *(const s16x4*)p;
  u.h[1] = *(const s16x4*)(p + 4);
  return u.v8;
}
__device__ __forceinline__ float tanh_fast(float z) {
  float e = __expf(2.f * z);
  return 1.f - 2.f / (e + 1.f);
}

__device__ __forceinline__ void mfma_chunk(const short* sW, const short* sS,
                                           int wv, int l15, int quad, int c,
                                           f32x4& acc0, f32x4& acc1) {
  const short* Brow  = sW + (wv * 16 + l15) * WSTR + c * KC + quad * 8;
  const short* Arow0 = sS + l15 * SSTR + quad * 8;
  const short* Arow1 = Arow0 + 16 * SSTR;
#pragma unroll
  for (int ks = 0; ks < 8; ++ks) {
    bf16x8 bfr = ld8(Brow  + ks * 32);
    bf16x8 a0  = ld8(Arow0 + ks * 32);
    bf16x8 a1  = ld8(Arow1 + ks * 32);
    acc0 = __builtin_amdgcn_mfma_f32_16x16x32_bf16(a0, bfr, acc0, 0, 0, 0);
    acc1 = __builtin_amdgcn_mfma_f32_16x16x32_bf16(a1, bfr, acc1, 0, 0, 0);
  }
}

__global__ void __launch_bounds__(256, 1)
rnn_persistent(const float* __restrict__ x, const float* __restrict__ Whx,
               const float* __restrict__ Whh, const float* __restrict__ bh,
               const float* __restrict__ Wph, const float* __restrict__ bp,
               float* __restrict__ out, unsigned short* hbuf, int* flags)
{
  extern __shared__ short smem[];
  short* sW = smem;                 // [JT][WSTR] bf16 W_hh slice, persistent
  short* sS = smem + JT * WSTR;     // [BT][SSTR] bf16 h k-chunk stage (+ hS overlay)

  const int tid  = threadIdx.x;
  const int bg   = blockIdx.x & 15;
  const int jg   = blockIdx.x >> 4;
  const int lane = tid & 63;
  const int wv   = tid >> 6;          // wave = n-tile (16 cols each)
  const int l15  = lane & 15;
  const int quad = lane >> 4;

  // ---- stage W_hh[jg*64 .. +64)[0..1024) into LDS as bf16 ----
  {
    const int jr = tid >> 2;
    const int kq = tid & 3;
    const float* src = Whh + (jg * JT + jr) * HID + kq * 256;
    short* dst = sW + jr * WSTR + kq * 256;
#pragma unroll 4
    for (int i = 0; i < 64; ++i) {
      float4 f = *(const float4*)(src + i * 4);
      s16x4 h4;
      h4.x = (short)f2bf(f.x); h4.y = (short)f2bf(f.y);
      h4.z = (short)f2bf(f.z); h4.w = (short)f2bf(f.w);
      *(s16x4*)(dst + i * 4) = h4;
    }
  }

  const int j = jg * JT + wv * 16 + l15;       // per-lane output column
  const float whx = Whx[j];
  const float bhv = bh[j];
  const int grow0 = bg * BT + quad * 4;        // global batch row base (acc row group 0)

  // staging thread mapping: 64 B per thread per chunk
  const int sr  = tid >> 3;               // 0..31 stage row
  const int seg = tid & 7;                // 0..7

  int* myflags = flags + bg * 64;         // 16 flags, one 64B line per bg

  for (int t = 0; t < SEQ; ++t) {
    const unsigned short* hin = hbuf + ((t + 1) & 1) * HBUF_HALVES;
    unsigned short*      hout = hbuf + (t & 1) * HBUF_HALVES;

    f32x4 acc0 = {0.f, 0.f, 0.f, 0.f};
    f32x4 acc1 = {0.f, 0.f, 0.f, 0.f};

    // x for this step (independent of peers) — issued before the spin,
    // drained by the spin/syncthreads so the vmcnt window below is clean.
    float xv0[4], xv1[4];
    {
      const float* xp = x + grow0 * SEQ + t;
#pragma unroll
      for (int rg = 0; rg < 4; ++rg) {
        xv0[rg] = xp[rg * SEQ];
        xv1[rg] = xp[(16 + rg) * SEQ];
      }
    }

    if (t > 0) {
      // acquire: wait for all 16 peers of this batch-group to finish step t-1
      if (tid < GJ) {
        while (load_flag(myflags + tid) < t) {}
      }
      // acquire-invalidate so plain h loads below can't hit stale L1/L2 lines
      if (tid == 0) cache_inv_l1l2();
      __syncthreads();   // full drain (vmcnt 0): inv complete, x loads retired

      const char* lbase = (const char*)(hin + (bg * BT + sr) * HID) + seg * 16;
      short* sdst = sS + sr * SSTR + seg * 8;

      i32x4 a0, a1, a2, a3, b0, b1, b2, b3, c0, c1, c2, c3, d0, d1, d2, d3;
      issue4(lbase,        a0, a1, a2, a3);   // chunk 0
      issue4(lbase + 512,  b0, b1, b2, b3);   // chunk 1
      issue4(lbase + 1024, c0, c1, c2, c3);   // chunk 2
      issue4(lbase + 1536, d0, d1, d2, d3);   // chunk 3

      // chunk 0 (stage free: post-spin __syncthreads was the barrier)
      wait_vm12(a0, a1, a2, a3);
      wr16(sdst, a0); wr16(sdst + 64, a1); wr16(sdst + 128, a2); wr16(sdst + 192, a3);
      barrier_lgkm();
      mfma_chunk(sW, sS, wv, l15, quad, 0, acc0, acc1);

      // chunk 1
      barrier_lgkm();                          // all waves done reading chunk 0
      wait_vm8(b0, b1, b2, b3);
      wr16(sdst, b0); wr16(sdst + 64, b1); wr16(sdst + 128, b2); wr16(sdst + 192, b3);
      barrier_lgkm();
      mfma_chunk(sW, sS, wv, l15, quad, 1, acc0, acc1);

      // chunk 2
      barrier_lgkm();
      wait_vm4(c0, c1, c2, c3);
      wr16(sdst, c0); wr16(sdst + 64, c1); wr16(sdst + 128, c2); wr16(sdst + 192, c3);
      barrier_lgkm();
      mfma_chunk(sW, sS, wv, l15, quad, 2, acc0, acc1);

      // chunk 3
      barrier_lgkm();
      wait_vm0(d0, d1, d2, d3);
      wr16(sdst, d0); wr16(sdst + 64, d1); wr16(sdst + 128, d2); wr16(sdst + 192, d3);
      barrier_lgkm();
      mfma_chunk(sW, sS, wv, l15, quad, 3, acc0, acc1);
    }

    // ---- epilogue: h = tanh(acc + x*whx + bh), exchange via LDS, coalesced store ----
    barrier_lgkm();     // chunk-3 stage reads done everywhere (sS reused as hS)
    {
      short* hS = sS;   // [BT][HSTR] overlay
#pragma unroll
      for (int rg = 0; rg < 4; ++rg) {
        float z0 = acc0[rg] + xv0[rg] * whx + bhv;
        hS[(quad * 4 + rg) * HSTR + wv * 16 + l15] = (short)f2bf(tanh_fast(z0));
        float z1 = acc1[rg] + xv1[rg] * whx + bhv;
        hS[(16 + quad * 4 + rg) * HSTR + wv * 16 + l15] = (short)f2bf(tanh_fast(z1));
      }
    }
    barrier_lgkm();
    {
      const short* hsrc = sS + sr * HSTR + seg * 8;
      u32x2 lo = *(const u32x2*)(hsrc);
      u32x2 hi = *(const u32x2*)(hsrc + 4);
      i32x4 sv; sv.x = (int)lo.x; sv.y = (int)lo.y; sv.z = (int)hi.x; sv.w = (int)hi.y;
      unsigned short* dst = hout + (bg * BT + sr) * HID + jg * JT + seg * 8;
      store16(dst, sv);
    }
    waitcnt0();          // this thread's 4KB-coalesced store retired at MALL
    barrier_lgkm();      // all threads retired before the flag release
    if (tid == 0) store_flag(myflags + jg, t + 1);
  }

  // ---- output head: out[b, jg*8+cc] = h_last . W_ph[c] + b_p ----
  if (tid < GJ) {
    while (load_flag(myflags + tid) < SEQ) {}
  }
  if (tid == 0) cache_inv_l1l2();   // h_last loads below are plain/cacheable
  __syncthreads();

  const unsigned short* hlast = hbuf + ((SEQ - 1) & 1) * HBUF_HALVES;
  const int cc = tid & 7;
  const int cg = jg * 8 + cc;
  const int hr = tid >> 3;
  float acc = 0.f;
  const char* lbase = (const char*)(hlast + (bg * BT + sr) * HID) + seg * 16;
  short* sdst = sS + sr * SSTR + seg * 8;
  for (int c = 0; c < 4; ++c) {
    __syncthreads();
    i32x4 p0, p1, p2, p3;
    issue4(lbase + c * 512, p0, p1, p2, p3);
    waitcnt0();
    wr16(sdst, p0); wr16(sdst + 64, p1); wr16(sdst + 128, p2); wr16(sdst + 192, p3);
    __syncthreads();
    const float* wp = Wph + cg * HID + c * KC;
    const short* hs = sS + hr * SSTR;
#pragma unroll 8
    for (int k4 = 0; k4 < 64; ++k4) {
      float4 w  = *(const float4*)(wp + k4 * 4);
      s16x4 hv  = *(const s16x4*)(hs + k4 * 4);
      acc += b2f(hv.x) * w.x + b2f(hv.y) * w.y + b2f(hv.z) * w.z + b2f(hv.w) * w.w;
    }
  }
  storef(&out[(bg * BT + hr) * CLS + cg], acc + bp[cg]);
}

extern "C" void kernel_launch(void* const* d_in, const int* in_sizes, int n_in,
                              void* d_out, int out_size, void* d_ws, size_t ws_size,
                              hipStream_t stream) {
  const float* x   = (const float*)d_in[0];
  const float* Whx = (const float*)d_in[1];
  const float* Whh = (const float*)d_in[2];
  const float* bh  = (const float*)d_in[3];
  const float* Wph = (const float*)d_in[4];
  const float* bp  = (const float*)d_in[5];
  float* out = (float*)d_out;

  unsigned short* hbuf = (unsigned short*)d_ws;
  int* flags = (int*)((char*)d_ws + (size_t)2 * HBUF_HALVES * 2);

  hipFuncSetAttribute(reinterpret_cast<const void*>(rnn_persistent),
                      hipFuncAttributeMaxDynamicSharedMemorySize, SMEM_BYTES);

  rnn_persistent<<<dim3(GB * GJ), dim3(256), SMEM_BYTES, stream>>>(
      x, Whx, Whh, bh, Wph, bp, out, hbuf, flags);
}

// Round 3
// 1228.366 us; speedup vs baseline: 1.2031x; 1.2031x over previous
//
#include <hip/hip_runtime.h>
#include <stdint.h>

// Persistent-kernel RNN: 256 wgs (1/CU), W_hh bf16 resident in LDS (16 j-slices),
// batch split 16 ways; h exchanged via MALL (all sc0 sc1).
// R5: FLAG-FREE sentinel exchange. h values are tanh outputs (never NaN), so
// consumers poll the h DATA itself: each 16B packet is written by one atomic
// store16; a packet equal to POISON (0xFFFF halves) means "not yet written".
// This deletes the per-step flag hop (store-drain + flag store + flag poll)
// ~1.5-2 MALL RTTs from the 256-step critical chain.
// 6 rotating buffers make the poison protocol raceless:
//   step t: read buf[(t-1)%6], write buf[t%6], poison own region of buf[(t+3)%6].
// Ordering (transitive over the data dependency):
//  (a) poison at step-t start is safe: readers of buf[(t+3)%6] (=h(t-3), read at
//      step t-2) are all done before any peer produced h(t-2), which is before
//      our step-t start.
//  (b) poison is drained by chunk-3's wait vmcnt(0) (t=0: explicit waitcnt0)
//      BEFORE the h store issues -> no consumer can observe pre-poison stale
//      data: its poll is ordered after the producer's poison-drain via
//      poison-drain -> h visible -> consumed -> ... -> poll.
// buf[0..2] are poisoned by a captured hipMemsetAsync(0xFF) each launch
// (covers first launch, graph replay, and reset()-zeroed workspace).
// R3 lesson: no sub-device coherence scope exists (sc0-only never becomes
// visible). R4 lesson: buffer_inv is a full-L2 invalidate -> thrash; reverted.

#define BATCH 512
#define SEQ   256
#define HID   1024
#define CLS   128

#define GB 16          // batch groups
#define GJ 16          // hidden slices
#define BT 32          // batch rows per wg
#define JT 64          // hidden cols per wg
#define KC 256         // k-chunk per stage buffer fill
#define WSTR 1028      // W LDS row stride (halves): 2-way banks, 8B aligned
#define SSTR 260       // stage row stride (halves)
#define HSTR 68        // h-store exchange row stride (halves)
#define NBUF 6         // rotating h buffers (poison protocol needs >=5; 6 = cheap mod)
#define XBSTR 33       // x-tile LDS row stride (floats)
#define SMEM_BYTES ((JT * WSTR + BT * SSTR) * 2 + BT * XBSTR * 4)   // 152448 B
#define HBUF_HALVES (BATCH * HID)                  // 1 MB per buffer

typedef __attribute__((ext_vector_type(8))) short  bf16x8;
typedef __attribute__((ext_vector_type(4))) short  s16x4;
typedef __attribute__((ext_vector_type(4))) float  f32x4;
typedef __attribute__((ext_vector_type(4))) int    i32x4;
typedef __attribute__((ext_vector_type(2))) unsigned int u32x2;

__device__ __forceinline__ unsigned short f2bf(float f) {
  unsigned int u = __float_as_uint(f);
  u = (u + 0x7FFFu + ((u >> 16) & 1u)) >> 16;   // RNE
  return (unsigned short)u;
}
__device__ __forceinline__ float b2f(short h) {
  return __uint_as_float(((unsigned int)(unsigned short)h) << 16);
}

// ---- device-coherent (MALL) accesses ----
__device__ __forceinline__ void store16(void* p, i32x4 v) {
  asm volatile("global_store_dwordx4 %0, %1, off sc0 sc1" :: "v"(p), "v"(v) : "memory");
}
__device__ __forceinline__ void waitcnt0() {
  asm volatile("s_waitcnt vmcnt(0)" ::: "memory");
}
// raw workgroup barrier: drains LDS ops only — global loads/stores stay in flight
__device__ __forceinline__ void barrier_lgkm() {
  asm volatile("s_waitcnt lgkmcnt(0)\n\ts_barrier" ::: "memory");
}
// issue 4x dwordx4 coherent loads (64 B/thread), no wait
__device__ __forceinline__ void issue4(const void* p, i32x4& a, i32x4& b, i32x4& c, i32x4& d) {
  asm volatile(
    "global_load_dwordx4 %0, %4, off sc0 sc1\n\t"
    "global_load_dwordx4 %1, %4, off offset:128 sc0 sc1\n\t"
    "global_load_dwordx4 %2, %4, off offset:256 sc0 sc1\n\t"
    "global_load_dwordx4 %3, %4, off offset:384 sc0 sc1"
    : "=&v"(a), "=&v"(b), "=&v"(c), "=&v"(d)
    : "v"(p) : "memory");
}
// counted waits, tying the chunk's registers so LDS writes can't be hoisted.
// vmcnt(N) semantics: everything except the youngest N ops is done. Exactly 12
// staging loads are younger than chunk0, 8 than chunk1, 4 than chunk2 — so the
// counts are correct regardless of how many OLDER ops (poison store, prev-step
// h store) are still in flight.
#define DEF_WAIT(NAME, N) \
__device__ __forceinline__ void NAME(i32x4& a, i32x4& b, i32x4& c, i32x4& d) { \
  asm volatile("s_waitcnt vmcnt(" #N ")" : "+v"(a), "+v"(b), "+v"(c), "+v"(d) :: "memory"); \
}
DEF_WAIT(wait_vm12, 12)
DEF_WAIT(wait_vm8, 8)
DEF_WAIT(wait_vm4, 4)
DEF_WAIT(wait_vm0, 0)

__device__ __forceinline__ void wr16(short* p, i32x4 v) {  // 16 B to LDS as 2x b64
  u32x2 lo, hi;
  lo.x = (unsigned)v.x; lo.y = (unsigned)v.y;
  hi.x = (unsigned)v.z; hi.y = (unsigned)v.w;
  *(u32x2*)p = lo;
  *(u32x2*)(p + 4) = hi;
}
__device__ __forceinline__ bf16x8 ld8(const short* p) {    // 8 bf16 from LDS as 2x b64
  union { bf16x8 v8; s16x4 h[2]; } u;
  u.h[0] = *(const s16x4*)p;
  u.h[1] = *(const s16x4*)(p + 4);
  return u.v8;
}
__device__ __forceinline__ float tanh_fast(float z) {
  float e = __expf(2.f * z);
  return 1.f - 2.f / (e + 1.f);
}

// POISON detection: each 16B packet comes from one atomic store16, so checking
// one bf16 half per packet suffices. 0xFFFF is -NaN: tanh output can never be
// NaN (inputs finite by induction), so half==0xFFFF <=> not yet written.
__device__ __forceinline__ bool poisoned4(const i32x4& a, const i32x4& b,
                                          const i32x4& c, const i32x4& d) {
  return ((a.x & 0xFFFF) == 0xFFFF) | ((b.x & 0xFFFF) == 0xFFFF) |
         ((c.x & 0xFFFF) == 0xFFFF) | ((d.x & 0xFFFF) == 0xFFFF);
}
__device__ __forceinline__ void retry4(const void* p, i32x4& a, i32x4& b,
                                       i32x4& c, i32x4& d) {
  do {
    asm volatile("s_sleep 1" ::: "memory");
    issue4(p, a, b, c, d);
    waitcnt0();
  } while (poisoned4(a, b, c, d));
}

__device__ __forceinline__ void mfma_chunk(const short* sW, const short* sS,
                                           int wv, int l15, int quad, int c,
                                           f32x4& acc0, f32x4& acc1) {
  const short* Brow  = sW + (wv * 16 + l15) * WSTR + c * KC + quad * 8;
  const short* Arow0 = sS + l15 * SSTR + quad * 8;
  const short* Arow1 = Arow0 + 16 * SSTR;
#pragma unroll
  for (int ks = 0; ks < 8; ++ks) {
    bf16x8 bfr = ld8(Brow  + ks * 32);
    bf16x8 a0  = ld8(Arow0 + ks * 32);
    bf16x8 a1  = ld8(Arow1 + ks * 32);
    acc0 = __builtin_amdgcn_mfma_f32_16x16x32_bf16(a0, bfr, acc0, 0, 0, 0);
    acc1 = __builtin_amdgcn_mfma_f32_16x16x32_bf16(a1, bfr, acc1, 0, 0, 0);
  }
}

__global__ void __launch_bounds__(256, 1)
rnn_persistent(const float* __restrict__ x, const float* __restrict__ Whx,
               const float* __restrict__ Whh, const float* __restrict__ bh,
               const float* __restrict__ Wph, const float* __restrict__ bp,
               float* __restrict__ out, unsigned short* hbuf)
{
  extern __shared__ short smem[];
  short* sW = smem;                 // [JT][WSTR] bf16 W_hh slice, persistent
  short* sS = smem + JT * WSTR;     // [BT][SSTR] bf16 h k-chunk stage (+ hS overlay)
  float* xb = (float*)(smem + JT * WSTR + BT * SSTR);  // [BT][XBSTR] x tile

  const int tid  = threadIdx.x;
  const int bg   = blockIdx.x & 15;
  const int jg   = blockIdx.x >> 4;
  const int lane = tid & 63;
  const int wv   = tid >> 6;          // wave = n-tile (16 cols each)
  const int l15  = lane & 15;
  const int quad = lane >> 4;

  // ---- stage W_hh[jg*64 .. +64)[0..1024) into LDS as bf16 ----
  {
    const int jr = tid >> 2;
    const int kq = tid & 3;
    const float* src = Whh + (jg * JT + jr) * HID + kq * 256;
    short* dst = sW + jr * WSTR + kq * 256;
#pragma unroll 4
    for (int i = 0; i < 64; ++i) {
      float4 f = *(const float4*)(src + i * 4);
      s16x4 h4;
      h4.x = (short)f2bf(f.x); h4.y = (short)f2bf(f.y);
      h4.z = (short)f2bf(f.z); h4.w = (short)f2bf(f.w);
      *(s16x4*)(dst + i * 4) = h4;
    }
  }

  const int j = jg * JT + wv * 16 + l15;       // per-lane output column
  const float whx = Whx[j];
  const float bhv = bh[j];

  // staging thread mapping: 64 B per thread per chunk
  const int sr  = tid >> 3;               // 0..31 stage row
  const int seg = tid & 7;                // 0..7

  // rotating buffer indices: bw=t%6 (write), br=(t-1)%6 (read), bz=(t+3)%6 (poison)
  int bw = 0, br = NBUF - 1, bz = 3;

  for (int t = 0; t < SEQ; ++t) {
    const unsigned short* hin = hbuf + br * HBUF_HALVES;
    unsigned short*      hout = hbuf + bw * HBUF_HALVES;

    // ---- x tile refill (every 32 steps): 32 rows x 32 steps into LDS ----
    if ((t & 31) == 0) {
      barrier_lgkm();                     // prior xb readers (and W-stage writes) done
      const int xr = tid >> 3;
      const int xc = (tid & 7) * 4;
      float4 xt = *(const float4*)(x + (bg * BT + xr) * SEQ + t + xc);
      xb[xr * XBSTR + xc + 0] = xt.x;
      xb[xr * XBSTR + xc + 1] = xt.y;
      xb[xr * XBSTR + xc + 2] = xt.z;
      xb[xr * XBSTR + xc + 3] = xt.w;
      __syncthreads();                    // tile visible (full drain, 8x total: cheap)
    }
    float xv0[4], xv1[4];
    {
      const int tc = t & 31;
#pragma unroll
      for (int rg = 0; rg < 4; ++rg) {
        xv0[rg] = xb[(quad * 4 + rg) * XBSTR + tc];
        xv1[rg] = xb[(16 + quad * 4 + rg) * XBSTR + tc];
      }
    }

    f32x4 acc0 = {0.f, 0.f, 0.f, 0.f};
    f32x4 acc1 = {0.f, 0.f, 0.f, 0.f};

    // ---- poison own region of buf[(t+3)%6] (safe per ordering (a)) ----
    {
      unsigned short* pb = hbuf + bz * HBUF_HALVES;
      i32x4 pv; pv.x = -1; pv.y = -1; pv.z = -1; pv.w = -1;
      store16(pb + (bg * BT + sr) * HID + jg * JT + seg * 8, pv);
    }

    if (t > 0) {
      const char* lbase = (const char*)(hin + (bg * BT + sr) * HID) + seg * 16;
      short* sdst = sS + sr * SSTR + seg * 8;

      i32x4 a0, a1, a2, a3, b0, b1, b2, b3, c0, c1, c2, c3, d0, d1, d2, d3;
      issue4(lbase,        a0, a1, a2, a3);   // chunk 0
      issue4(lbase + 512,  b0, b1, b2, b3);   // chunk 1
      issue4(lbase + 1024, c0, c1, c2, c3);   // chunk 2
      issue4(lbase + 1536, d0, d1, d2, d3);   // chunk 3

      // chunk 0 — on poison (all-peers-lagging common case) retry ALL chunks
      wait_vm12(a0, a1, a2, a3);
      if (__builtin_expect(poisoned4(a0, a1, a2, a3), 0)) {
        waitcnt0();
        do {
          asm volatile("s_sleep 1" ::: "memory");
          issue4(lbase,        a0, a1, a2, a3);
          issue4(lbase + 512,  b0, b1, b2, b3);
          issue4(lbase + 1024, c0, c1, c2, c3);
          issue4(lbase + 1536, d0, d1, d2, d3);
          waitcnt0();
        } while (poisoned4(a0, a1, a2, a3) || poisoned4(b0, b1, b2, b3) ||
                 poisoned4(c0, c1, c2, c3) || poisoned4(d0, d1, d2, d3));
      }
      wr16(sdst, a0); wr16(sdst + 64, a1); wr16(sdst + 128, a2); wr16(sdst + 192, a3);
      barrier_lgkm();
      mfma_chunk(sW, sS, wv, l15, quad, 0, acc0, acc1);

      // chunk 1
      barrier_lgkm();                          // all waves done reading chunk 0
      wait_vm8(b0, b1, b2, b3);
      if (__builtin_expect(poisoned4(b0, b1, b2, b3), 0)) {
        waitcnt0(); retry4(lbase + 512, b0, b1, b2, b3);
      }
      wr16(sdst, b0); wr16(sdst + 64, b1); wr16(sdst + 128, b2); wr16(sdst + 192, b3);
      barrier_lgkm();
      mfma_chunk(sW, sS, wv, l15, quad, 1, acc0, acc1);

      // chunk 2
      barrier_lgkm();
      wait_vm4(c0, c1, c2, c3);
      if (__builtin_expect(poisoned4(c0, c1, c2, c3), 0)) {
        waitcnt0(); retry4(lbase + 1024, c0, c1, c2, c3);
      }
      wr16(sdst, c0); wr16(sdst + 64, c1); wr16(sdst + 128, c2); wr16(sdst + 192, c3);
      barrier_lgkm();
      mfma_chunk(sW, sS, wv, l15, quad, 2, acc0, acc1);

      // chunk 3 — wait_vm0 also drains this step's poison store (ordering (b))
      barrier_lgkm();
      wait_vm0(d0, d1, d2, d3);
      if (__builtin_expect(poisoned4(d0, d1, d2, d3), 0)) {
        retry4(lbase + 1536, d0, d1, d2, d3);
      }
      wr16(sdst, d0); wr16(sdst + 64, d1); wr16(sdst + 128, d2); wr16(sdst + 192, d3);
      barrier_lgkm();
      mfma_chunk(sW, sS, wv, l15, quad, 3, acc0, acc1);
    }

    // ---- epilogue: h = tanh(acc + x*whx + bh), exchange via LDS, coalesced store ----
    barrier_lgkm();     // chunk-3 stage reads done everywhere (sS reused as hS)
    {
      short* hS = sS;   // [BT][HSTR] overlay
#pragma unroll
      for (int rg = 0; rg < 4; ++rg) {
        float z0 = acc0[rg] + xv0[rg] * whx + bhv;
        hS[(quad * 4 + rg) * HSTR + wv * 16 + l15] = (short)f2bf(tanh_fast(z0));
        float z1 = acc1[rg] + xv1[rg] * whx + bhv;
        hS[(16 + quad * 4 + rg) * HSTR + wv * 16 + l15] = (short)f2bf(tanh_fast(z1));
      }
    }
    barrier_lgkm();
    {
      const short* hsrc = sS + sr * HSTR + seg * 8;
      u32x2 lo = *(const u32x2*)(hsrc);
      u32x2 hi = *(const u32x2*)(hsrc + 4);
      i32x4 sv; sv.x = (int)lo.x; sv.y = (int)lo.y; sv.z = (int)hi.x; sv.w = (int)hi.y;
      if (t == 0) waitcnt0();   // t=0 has no wait_vm0: drain poison before h visible
      unsigned short* dst = hout + (bg * BT + sr) * HID + jg * JT + seg * 8;
      store16(dst, sv);         // release: no drain, no flag — the data IS the flag
    }
    barrier_lgkm();             // LDS-exchange reads done before next-step sS reuse

    bw = (bw + 1 == NBUF) ? 0 : bw + 1;
    br = (br + 1 == NBUF) ? 0 : br + 1;
    bz = (bz + 1 == NBUF) ? 0 : bz + 1;
  }

  // ---- output head: out[b, jg*8+cc] = h_last . W_ph[c] + b_p ----
  const unsigned short* hlast = hbuf + ((SEQ - 1) % NBUF) * HBUF_HALVES;
  const int cc = tid & 7;
  const int cg = jg * 8 + cc;
  const int hr = tid >> 3;
  float acc = 0.f;
  const char* lbase = (const char*)(hlast + (bg * BT + sr) * HID) + seg * 16;
  short* sdst = sS + sr * SSTR + seg * 8;
  for (int c = 0; c < 4; ++c) {
    __syncthreads();
    i32x4 p0, p1, p2, p3;
    issue4(lbase + c * 512, p0, p1, p2, p3);
    waitcnt0();
    if (poisoned4(p0, p1, p2, p3)) retry4(lbase + c * 512, p0, p1, p2, p3);
    wr16(sdst, p0); wr16(sdst + 64, p1); wr16(sdst + 128, p2); wr16(sdst + 192, p3);
    __syncthreads();
    const float* wp = Wph + cg * HID + c * KC;
    const short* hs = sS + hr * SSTR;
#pragma unroll 8
    for (int k4 = 0; k4 < 64; ++k4) {
      float4 w  = *(const float4*)(wp + k4 * 4);
      s16x4 hv  = *(const s16x4*)(hs + k4 * 4);
      acc += b2f(hv.x) * w.x + b2f(hv.y) * w.y + b2f(hv.z) * w.z + b2f(hv.w) * w.w;
    }
  }
  out[(bg * BT + hr) * CLS + cg] = acc + bp[cg];
}

extern "C" void kernel_launch(void* const* d_in, const int* in_sizes, int n_in,
                              void* d_out, int out_size, void* d_ws, size_t ws_size,
                              hipStream_t stream) {
  const float* x   = (const float*)d_in[0];
  const float* Whx = (const float*)d_in[1];
  const float* Whh = (const float*)d_in[2];
  const float* bh  = (const float*)d_in[3];
  const float* Wph = (const float*)d_in[4];
  const float* bp  = (const float*)d_in[5];
  float* out = (float*)d_out;

  unsigned short* hbuf = (unsigned short*)d_ws;

  // Poison buf[0..2]: their first use as a write-target (t=0,1,2) precedes any
  // in-kernel poison of them; consumers at t=1,2,3 must see poison, not stale
  // data (previous run / reset()-zeroed workspace). Captured, stream-ordered.
  hipMemsetAsync(d_ws, 0xFF, (size_t)3 * HBUF_HALVES * 2, stream);

  hipFuncSetAttribute(reinterpret_cast<const void*>(rnn_persistent),
                      hipFuncAttributeMaxDynamicSharedMemorySize, SMEM_BYTES);

  rnn_persistent<<<dim3(GB * GJ), dim3(256), SMEM_BYTES, stream>>>(
      x, Whx, Whh, bh, Wph, bp, out, hbuf);
}

// Round 4
// 1227.493 us; speedup vs baseline: 1.2040x; 1.0007x over previous
//
#include <hip/hip_runtime.h>
#include <stdint.h>

// Persistent-kernel RNN: 256 wgs (1/CU), W_hh bf16 resident in LDS (16 j-slices),
// batch split 16 ways; h exchanged via MALL.
// R6: AGENT-scope exchange (sc1 only). The previous rounds used sc0 sc1 =
// SYSTEM scope: rocprof showed WRITE_SIZE == exact h+poison store volume, i.e.
// every exchange store wrote through MALL into HBM, and every serialized hop
// (store drain, flag/data visibility, consumer poll, h load) ran at HBM RTT.
// sc1 alone = agent scope (what the compiler emits for device-scope atomics):
// loads bypass L1+L2 and read the MALL; stores write through to the MALL and
// STOP there. Agent scope is exactly sufficient — all 256 wgs are on one GPU.
// (R3 lesson: sc0 alone = CU/SE scope is too weak — never visible. sc1 alone
// was never tried before this round.)
// R5 structure retained: FLAG-FREE sentinel exchange. h values are tanh
// outputs (never NaN); consumers poll the h DATA itself. Each 16B packet is
// one atomic store16; POISON (0xFFFF halves) means "not yet written".
// 6 rotating buffers:
//   step t: read buf[(t-1)%6], write buf[t%6], poison own region of buf[(t+3)%6].
// Ordering:
//  (a) poison at step-t start is safe: readers of buf[(t+3)%6] (=h(t-3), read at
//      step t-2) all finished before any peer produced h(t-2) -> before our t.
//  (b) poison is drained by chunk-3's wait vmcnt(0) (t=0: explicit waitcnt0)
//      BEFORE the h store issues -> consumer poll can never see pre-poison
//      stale data (poll is ordered after poison-drain transitively).
// buf[0..2] poisoned by captured hipMemsetAsync(0xFF) each launch.

#define BATCH 512
#define SEQ   256
#define HID   1024
#define CLS   128

#define GB 16          // batch groups
#define GJ 16          // hidden slices
#define BT 32          // batch rows per wg
#define JT 64          // hidden cols per wg
#define KC 256         // k-chunk per stage buffer fill
#define WSTR 1028      // W LDS row stride (halves): 2-way banks, 8B aligned
#define SSTR 260       // stage row stride (halves)
#define HSTR 68        // h-store exchange row stride (halves)
#define NBUF 6         // rotating h buffers (poison protocol needs >=5; 6 = cheap mod)
#define XBSTR 33       // x-tile LDS row stride (floats)
#define SMEM_BYTES ((JT * WSTR + BT * SSTR) * 2 + BT * XBSTR * 4)   // 152448 B
#define HBUF_HALVES (BATCH * HID)                  // 1 MB per buffer

typedef __attribute__((ext_vector_type(8))) short  bf16x8;
typedef __attribute__((ext_vector_type(4))) short  s16x4;
typedef __attribute__((ext_vector_type(4))) float  f32x4;
typedef __attribute__((ext_vector_type(4))) int    i32x4;
typedef __attribute__((ext_vector_type(2))) unsigned int u32x2;

__device__ __forceinline__ unsigned short f2bf(float f) {
  unsigned int u = __float_as_uint(f);
  u = (u + 0x7FFFu + ((u >> 16) & 1u)) >> 16;   // RNE
  return (unsigned short)u;
}
__device__ __forceinline__ float b2f(short h) {
  return __uint_as_float(((unsigned int)(unsigned short)h) << 16);
}

// ---- agent-scope (MALL-coherent, sc1) exchange accesses ----
__device__ __forceinline__ void store16(void* p, i32x4 v) {
  asm volatile("global_store_dwordx4 %0, %1, off sc1" :: "v"(p), "v"(v) : "memory");
}
__device__ __forceinline__ void waitcnt0() {
  asm volatile("s_waitcnt vmcnt(0)" ::: "memory");
}
// raw workgroup barrier: drains LDS ops only — global loads/stores stay in flight
__device__ __forceinline__ void barrier_lgkm() {
  asm volatile("s_waitcnt lgkmcnt(0)\n\ts_barrier" ::: "memory");
}
// issue 4x dwordx4 agent-coherent loads (64 B/thread), no wait
__device__ __forceinline__ void issue4(const void* p, i32x4& a, i32x4& b, i32x4& c, i32x4& d) {
  asm volatile(
    "global_load_dwordx4 %0, %4, off sc1\n\t"
    "global_load_dwordx4 %1, %4, off offset:128 sc1\n\t"
    "global_load_dwordx4 %2, %4, off offset:256 sc1\n\t"
    "global_load_dwordx4 %3, %4, off offset:384 sc1"
    : "=&v"(a), "=&v"(b), "=&v"(c), "=&v"(d)
    : "v"(p) : "memory");
}
// counted waits, tying the chunk's registers so LDS writes can't be hoisted.
// vmcnt(N): everything except the youngest N ops is done. Exactly 12 staging
// loads are younger than chunk0, 8 than chunk1, 4 than chunk2 — counts are
// correct regardless of how many OLDER ops (poison store, prev h store) are
// still in flight.
#define DEF_WAIT(NAME, N) \
__device__ __forceinline__ void NAME(i32x4& a, i32x4& b, i32x4& c, i32x4& d) { \
  asm volatile("s_waitcnt vmcnt(" #N ")" : "+v"(a), "+v"(b), "+v"(c), "+v"(d) :: "memory"); \
}
DEF_WAIT(wait_vm12, 12)
DEF_WAIT(wait_vm8, 8)
DEF_WAIT(wait_vm4, 4)
DEF_WAIT(wait_vm0, 0)

__device__ __forceinline__ void wr16(short* p, i32x4 v) {  // 16 B to LDS as 2x b64
  u32x2 lo, hi;
  lo.x = (unsigned)v.x; lo.y = (unsigned)v.y;
  hi.x = (unsigned)v.z; hi.y = (unsigned)v.w;
  *(u32x2*)p = lo;
  *(u32x2*)(p + 4) = hi;
}
__device__ __forceinline__ bf16x8 ld8(const short* p) {    // 8 bf16 from LDS as 2x b64
  union { bf16x8 v8; s16x4 h[2]; } u;
  u.h[0] = *(const s16x4*)p;
  u.h[1] = *(const s16x4*)(p + 4);
  return u.v8;
}
__device__ __forceinline__ float tanh_fast(float z) {
  float e = __expf(2.f * z);
  return 1.f - 2.f / (e + 1.f);
}

// POISON detection: each 16B packet comes from one atomic store16, so checking
// one bf16 half per packet suffices. 0xFFFF is -NaN: tanh output can never be
// NaN (inputs finite by induction), so half==0xFFFF <=> not yet written.
__device__ __forceinline__ bool poisoned4(const i32x4& a, const i32x4& b,
                                          const i32x4& c, const i32x4& d) {
  return ((a.x & 0xFFFF) == 0xFFFF) | ((b.x & 0xFFFF) == 0xFFFF) |
         ((c.x & 0xFFFF) == 0xFFFF) | ((d.x & 0xFFFF) == 0xFFFF);
}
__device__ __forceinline__ void retry4(const void* p, i32x4& a, i32x4& b,
                                       i32x4& c, i32x4& d) {
  do {
    asm volatile("s_sleep 1" ::: "memory");
    issue4(p, a, b, c, d);
    waitcnt0();
  } while (poisoned4(a, b, c, d));
}

__device__ __forceinline__ void mfma_chunk(const short* sW, const short* sS,
                                           int wv, int l15, int quad, int c,
                                           f32x4& acc0, f32x4& acc1) {
  const short* Brow  = sW + (wv * 16 + l15) * WSTR + c * KC + quad * 8;
  const short* Arow0 = sS + l15 * SSTR + quad * 8;
  const short* Arow1 = Arow0 + 16 * SSTR;
#pragma unroll
  for (int ks = 0; ks < 8; ++ks) {
    bf16x8 bfr = ld8(Brow  + ks * 32);
    bf16x8 a0  = ld8(Arow0 + ks * 32);
    bf16x8 a1  = ld8(Arow1 + ks * 32);
    acc0 = __builtin_amdgcn_mfma_f32_16x16x32_bf16(a0, bfr, acc0, 0, 0, 0);
    acc1 = __builtin_amdgcn_mfma_f32_16x16x32_bf16(a1, bfr, acc1, 0, 0, 0);
  }
}

__global__ void __launch_bounds__(256, 1)
rnn_persistent(const float* __restrict__ x, const float* __restrict__ Whx,
               const float* __restrict__ Whh, const float* __restrict__ bh,
               const float* __restrict__ Wph, const float* __restrict__ bp,
               float* __restrict__ out, unsigned short* hbuf)
{
  extern __shared__ short smem[];
  short* sW = smem;                 // [JT][WSTR] bf16 W_hh slice, persistent
  short* sS = smem + JT * WSTR;     // [BT][SSTR] bf16 h k-chunk stage (+ hS overlay)
  float* xb = (float*)(smem + JT * WSTR + BT * SSTR);  // [BT][XBSTR] x tile

  const int tid  = threadIdx.x;
  const int bg   = blockIdx.x & 15;
  const int jg   = blockIdx.x >> 4;
  const int lane = tid & 63;
  const int wv   = tid >> 6;          // wave = n-tile (16 cols each)
  const int l15  = lane & 15;
  const int quad = lane >> 4;

  // ---- stage W_hh[jg*64 .. +64)[0..1024) into LDS as bf16 ----
  {
    const int jr = tid >> 2;
    const int kq = tid & 3;
    const float* src = Whh + (jg * JT + jr) * HID + kq * 256;
    short* dst = sW + jr * WSTR + kq * 256;
#pragma unroll 4
    for (int i = 0; i < 64; ++i) {
      float4 f = *(const float4*)(src + i * 4);
      s16x4 h4;
      h4.x = (short)f2bf(f.x); h4.y = (short)f2bf(f.y);
      h4.z = (short)f2bf(f.z); h4.w = (short)f2bf(f.w);
      *(s16x4*)(dst + i * 4) = h4;
    }
  }

  const int j = jg * JT + wv * 16 + l15;       // per-lane output column
  const float whx = Whx[j];
  const float bhv = bh[j];

  // staging thread mapping: 64 B per thread per chunk
  const int sr  = tid >> 3;               // 0..31 stage row
  const int seg = tid & 7;                // 0..7

  // rotating buffer indices: bw=t%6 (write), br=(t-1)%6 (read), bz=(t+3)%6 (poison)
  int bw = 0, br = NBUF - 1, bz = 3;

  for (int t = 0; t < SEQ; ++t) {
    const unsigned short* hin = hbuf + br * HBUF_HALVES;
    unsigned short*      hout = hbuf + bw * HBUF_HALVES;

    // ---- x tile refill (every 32 steps): 32 rows x 32 steps into LDS ----
    if ((t & 31) == 0) {
      barrier_lgkm();                     // prior xb readers (and W-stage writes) done
      const int xr = tid >> 3;
      const int xc = (tid & 7) * 4;
      float4 xt = *(const float4*)(x + (bg * BT + xr) * SEQ + t + xc);
      xb[xr * XBSTR + xc + 0] = xt.x;
      xb[xr * XBSTR + xc + 1] = xt.y;
      xb[xr * XBSTR + xc + 2] = xt.z;
      xb[xr * XBSTR + xc + 3] = xt.w;
      __syncthreads();                    // tile visible (full drain, 8x total: cheap)
    }
    float xv0[4], xv1[4];
    {
      const int tc = t & 31;
#pragma unroll
      for (int rg = 0; rg < 4; ++rg) {
        xv0[rg] = xb[(quad * 4 + rg) * XBSTR + tc];
        xv1[rg] = xb[(16 + quad * 4 + rg) * XBSTR + tc];
      }
    }

    f32x4 acc0 = {0.f, 0.f, 0.f, 0.f};
    f32x4 acc1 = {0.f, 0.f, 0.f, 0.f};

    // ---- poison own region of buf[(t+3)%6] (safe per ordering (a)) ----
    {
      unsigned short* pb = hbuf + bz * HBUF_HALVES;
      i32x4 pv; pv.x = -1; pv.y = -1; pv.z = -1; pv.w = -1;
      store16(pb + (bg * BT + sr) * HID + jg * JT + seg * 8, pv);
    }

    if (t > 0) {
      const char* lbase = (const char*)(hin + (bg * BT + sr) * HID) + seg * 16;
      short* sdst = sS + sr * SSTR + seg * 8;

      i32x4 a0, a1, a2, a3, b0, b1, b2, b3, c0, c1, c2, c3, d0, d1, d2, d3;
      issue4(lbase,        a0, a1, a2, a3);   // chunk 0
      issue4(lbase + 512,  b0, b1, b2, b3);   // chunk 1
      issue4(lbase + 1024, c0, c1, c2, c3);   // chunk 2
      issue4(lbase + 1536, d0, d1, d2, d3);   // chunk 3

      // chunk 0 — on poison (all-peers-lagging common case) retry ALL chunks
      wait_vm12(a0, a1, a2, a3);
      if (__builtin_expect(poisoned4(a0, a1, a2, a3), 0)) {
        waitcnt0();
        do {
          asm volatile("s_sleep 1" ::: "memory");
          issue4(lbase,        a0, a1, a2, a3);
          issue4(lbase + 512,  b0, b1, b2, b3);
          issue4(lbase + 1024, c0, c1, c2, c3);
          issue4(lbase + 1536, d0, d1, d2, d3);
          waitcnt0();
        } while (poisoned4(a0, a1, a2, a3) || poisoned4(b0, b1, b2, b3) ||
                 poisoned4(c0, c1, c2, c3) || poisoned4(d0, d1, d2, d3));
      }
      wr16(sdst, a0); wr16(sdst + 64, a1); wr16(sdst + 128, a2); wr16(sdst + 192, a3);
      barrier_lgkm();
      mfma_chunk(sW, sS, wv, l15, quad, 0, acc0, acc1);

      // chunk 1
      barrier_lgkm();                          // all waves done reading chunk 0
      wait_vm8(b0, b1, b2, b3);
      if (__builtin_expect(poisoned4(b0, b1, b2, b3), 0)) {
        waitcnt0(); retry4(lbase + 512, b0, b1, b2, b3);
      }
      wr16(sdst, b0); wr16(sdst + 64, b1); wr16(sdst + 128, b2); wr16(sdst + 192, b3);
      barrier_lgkm();
      mfma_chunk(sW, sS, wv, l15, quad, 1, acc0, acc1);

      // chunk 2
      barrier_lgkm();
      wait_vm4(c0, c1, c2, c3);
      if (__builtin_expect(poisoned4(c0, c1, c2, c3), 0)) {
        waitcnt0(); retry4(lbase + 1024, c0, c1, c2, c3);
      }
      wr16(sdst, c0); wr16(sdst + 64, c1); wr16(sdst + 128, c2); wr16(sdst + 192, c3);
      barrier_lgkm();
      mfma_chunk(sW, sS, wv, l15, quad, 2, acc0, acc1);

      // chunk 3 — wait_vm0 also drains this step's poison store (ordering (b))
      barrier_lgkm();
      wait_vm0(d0, d1, d2, d3);
      if (__builtin_expect(poisoned4(d0, d1, d2, d3), 0)) {
        retry4(lbase + 1536, d0, d1, d2, d3);
      }
      wr16(sdst, d0); wr16(sdst + 64, d1); wr16(sdst + 128, d2); wr16(sdst + 192, d3);
      barrier_lgkm();
      mfma_chunk(sW, sS, wv, l15, quad, 3, acc0, acc1);
    }

    // ---- epilogue: h = tanh(acc + x*whx + bh), exchange via LDS, coalesced store ----
    barrier_lgkm();     // chunk-3 stage reads done everywhere (sS reused as hS)
    {
      short* hS = sS;   // [BT][HSTR] overlay
#pragma unroll
      for (int rg = 0; rg < 4; ++rg) {
        float z0 = acc0[rg] + xv0[rg] * whx + bhv;
        hS[(quad * 4 + rg) * HSTR + wv * 16 + l15] = (short)f2bf(tanh_fast(z0));
        float z1 = acc1[rg] + xv1[rg] * whx + bhv;
        hS[(16 + quad * 4 + rg) * HSTR + wv * 16 + l15] = (short)f2bf(tanh_fast(z1));
      }
    }
    barrier_lgkm();
    {
      const short* hsrc = sS + sr * HSTR + seg * 8;
      u32x2 lo = *(const u32x2*)(hsrc);
      u32x2 hi = *(const u32x2*)(hsrc + 4);
      i32x4 sv; sv.x = (int)lo.x; sv.y = (int)lo.y; sv.z = (int)hi.x; sv.w = (int)hi.y;
      if (t == 0) waitcnt0();   // t=0 has no wait_vm0: drain poison before h visible
      unsigned short* dst = hout + (bg * BT + sr) * HID + jg * JT + seg * 8;
      store16(dst, sv);         // release: no drain, no flag — the data IS the flag
    }
    barrier_lgkm();             // LDS-exchange reads done before next-step sS reuse

    bw = (bw + 1 == NBUF) ? 0 : bw + 1;
    br = (br + 1 == NBUF) ? 0 : br + 1;
    bz = (bz + 1 == NBUF) ? 0 : bz + 1;
  }

  // ---- output head: out[b, jg*8+cc] = h_last . W_ph[c] + b_p ----
  const unsigned short* hlast = hbuf + ((SEQ - 1) % NBUF) * HBUF_HALVES;
  const int cc = tid & 7;
  const int cg = jg * 8 + cc;
  const int hr = tid >> 3;
  float acc = 0.f;
  const char* lbase = (const char*)(hlast + (bg * BT + sr) * HID) + seg * 16;
  short* sdst = sS + sr * SSTR + seg * 8;
  for (int c = 0; c < 4; ++c) {
    __syncthreads();
    i32x4 p0, p1, p2, p3;
    issue4(lbase + c * 512, p0, p1, p2, p3);
    waitcnt0();
    if (poisoned4(p0, p1, p2, p3)) retry4(lbase + c * 512, p0, p1, p2, p3);
    wr16(sdst, p0); wr16(sdst + 64, p1); wr16(sdst + 128, p2); wr16(sdst + 192, p3);
    __syncthreads();
    const float* wp = Wph + cg * HID + c * KC;
    const short* hs = sS + hr * SSTR;
#pragma unroll 8
    for (int k4 = 0; k4 < 64; ++k4) {
      float4 w  = *(const float4*)(wp + k4 * 4);
      s16x4 hv  = *(const s16x4*)(hs + k4 * 4);
      acc += b2f(hv.x) * w.x + b2f(hv.y) * w.y + b2f(hv.z) * w.z + b2f(hv.w) * w.w;
    }
  }
  out[(bg * BT + hr) * CLS + cg] = acc + bp[cg];
}

extern "C" void kernel_launch(void* const* d_in, const int* in_sizes, int n_in,
                              void* d_out, int out_size, void* d_ws, size_t ws_size,
                              hipStream_t stream) {
  const float* x   = (const float*)d_in[0];
  const float* Whx = (const float*)d_in[1];
  const float* Whh = (const float*)d_in[2];
  const float* bh  = (const float*)d_in[3];
  const float* Wph = (const float*)d_in[4];
  const float* bp  = (const float*)d_in[5];
  float* out = (float*)d_out;

  unsigned short* hbuf = (unsigned short*)d_ws;

  // Poison buf[0..2]: their first use as a write-target (t=0,1,2) precedes any
  // in-kernel poison of them; consumers at t=1,2,3 must see poison, not stale
  // data (previous run / reset()-zeroed workspace). Captured, stream-ordered.
  hipMemsetAsync(d_ws, 0xFF, (size_t)3 * HBUF_HALVES * 2, stream);

  hipFuncSetAttribute(reinterpret_cast<const void*>(rnn_persistent),
                      hipFuncAttributeMaxDynamicSharedMemorySize, SMEM_BYTES);

  rnn_persistent<<<dim3(GB * GJ), dim3(256), SMEM_BYTES, stream>>>(
      x, Whx, Whh, bh, Wph, bp, out, hbuf);
}

// Round 5
// 1107.425 us; speedup vs baseline: 1.3345x; 1.1084x over previous
//
#include <hip/hip_runtime.h>
#include <stdint.h>

// Persistent-kernel RNN: 256 wgs (1/CU), W_hh bf16 resident in LDS (16 j-slices),
// batch split 16 ways; h exchanged through the per-XCD L2 with device-scope flags.
// R7: L2-CACHED h exchange.
//   Evidence R5==R6 (sc0sc1 vs sc1-only: identical dur and counters): the
//   exchange runs at the MALL either way; the load phase is the 16x read
//   amplification (256 wgs x 64KB = 16 MB/step burst) riding the MALL.
//   All 16 readers of a bg's h are blockIdx==bg (mod 16) -> one XCD under
//   round-robin dispatch (XCD = blockIdx%8). Producer h-stores are sc1
//   write-THROUGH: they update the (shared) XCD L2 en route to the MALL.
//   So consumer h loads go PLAIN (L1/L2 cacheable); L1 staleness is killed by
//   a per-step buffer_inv sc0 (PRIVATE per-CU L1 invalidate — R4's mistake was
//   sc1 = shared-L2 nuke; with 1 wg/CU we own L1 and nothing hot lives in it).
//   Flag protocol stays R2/R6: release = h store sc1 -> waitcnt0 -> barrier ->
//   flag store sc1; acquire = flag spin (sc1, vmcnt0) -> L1-inv -> barrier.
// Staleness audit: L1 lines die by the inv; L2 lines are refreshed by the
// same-XCD producer's write-through, or enter fresh via post-flag miss->MALL.
// If dispatch placement or write-through semantics differ, h goes stale ->
// loud absmax failure (not a hang: no data-spin, flags are proven visible).
// R3 lesson: sc0-only spin hangs (sc0 load can sit in stale L1 forever).

#define BATCH 512
#define SEQ   256
#define HID   1024
#define CLS   128

#define GB 16          // batch groups
#define GJ 16          // hidden slices
#define BT 32          // batch rows per wg
#define JT 64          // hidden cols per wg
#define KC 256         // k-chunk per stage buffer fill
#define WSTR 1028      // W LDS row stride (halves): 2-way banks, 8B aligned
#define SSTR 260       // stage row stride (halves)
#define HSTR 68        // h-store exchange row stride (halves)
#define XBSTR 33       // x-tile LDS row stride (floats)
#define SMEM_BYTES ((JT * WSTR + BT * SSTR) * 2 + BT * XBSTR * 4)   // 152448 B
#define HBUF_HALVES (BATCH * HID)                  // 1 MB per buffer

typedef __attribute__((ext_vector_type(8))) short  bf16x8;
typedef __attribute__((ext_vector_type(4))) short  s16x4;
typedef __attribute__((ext_vector_type(4))) float  f32x4;
typedef __attribute__((ext_vector_type(4))) int    i32x4;
typedef __attribute__((ext_vector_type(2))) unsigned int u32x2;

__device__ __forceinline__ unsigned short f2bf(float f) {
  unsigned int u = __float_as_uint(f);
  u = (u + 0x7FFFu + ((u >> 16) & 1u)) >> 16;   // RNE
  return (unsigned short)u;
}
__device__ __forceinline__ float b2f(short h) {
  return __uint_as_float(((unsigned int)(unsigned short)h) << 16);
}

// ---- agent-scope (sc1) protocol accesses: R6-proven visible device-wide ----
__device__ __forceinline__ void store_flag(int* p, int v) {
  asm volatile("global_store_dword %0, %1, off sc1" :: "v"(p), "v"(v) : "memory");
}
__device__ __forceinline__ int load_flag(const int* p) {
  int v;
  asm volatile("global_load_dword %0, %1, off sc1\n\t"
               "s_waitcnt vmcnt(0)" : "=v"(v) : "v"(p) : "memory");
  return v;
}
// h store: sc1 write-through -> updates own-XCD L2 AND reaches the MALL.
__device__ __forceinline__ void store16(void* p, i32x4 v) {
  asm volatile("global_store_dwordx4 %0, %1, off sc1" :: "v"(p), "v"(v) : "memory");
}
__device__ __forceinline__ void waitcnt0() {
  asm volatile("s_waitcnt vmcnt(0)" ::: "memory");
}
// private L1 invalidate (sc0 ONLY — per-CU cache, not the shared L2), with an
// in-asm drain so the following __syncthreads provably orders it before any
// other wave's post-barrier loads.
__device__ __forceinline__ void l1_inv_wait() {
  asm volatile("buffer_inv sc0\n\ts_waitcnt vmcnt(0)" ::: "memory");
}
// raw workgroup barrier: drains LDS ops only — global loads/stores stay in flight
__device__ __forceinline__ void barrier_lgkm() {
  asm volatile("s_waitcnt lgkmcnt(0)\n\ts_barrier" ::: "memory");
}
// issue 4x dwordx4 PLAIN (L1/L2-cacheable) loads (64 B/thread), no wait.
// Fresh because: L1 was invalidated this step; L2 was updated by the same-XCD
// producer's sc1 write-through (flag observed => write completed).
__device__ __forceinline__ void issue4(const void* p, i32x4& a, i32x4& b, i32x4& c, i32x4& d) {
  asm volatile(
    "global_load_dwordx4 %0, %4, off\n\t"
    "global_load_dwordx4 %1, %4, off offset:128\n\t"
    "global_load_dwordx4 %2, %4, off offset:256\n\t"
    "global_load_dwordx4 %3, %4, off offset:384"
    : "=&v"(a), "=&v"(b), "=&v"(c), "=&v"(d)
    : "v"(p) : "memory");
}
// counted waits, tying the chunk's registers so LDS writes can't be hoisted.
// vmcnt(N): everything except the youngest N ops is done. Exactly 12 staging
// loads are younger than chunk0, 8 than chunk1, 4 than chunk2.
#define DEF_WAIT(NAME, N) \
__device__ __forceinline__ void NAME(i32x4& a, i32x4& b, i32x4& c, i32x4& d) { \
  asm volatile("s_waitcnt vmcnt(" #N ")" : "+v"(a), "+v"(b), "+v"(c), "+v"(d) :: "memory"); \
}
DEF_WAIT(wait_vm12, 12)
DEF_WAIT(wait_vm8, 8)
DEF_WAIT(wait_vm4, 4)
DEF_WAIT(wait_vm0, 0)

__device__ __forceinline__ void wr16(short* p, i32x4 v) {  // 16 B to LDS as 2x b64
  u32x2 lo, hi;
  lo.x = (unsigned)v.x; lo.y = (unsigned)v.y;
  hi.x = (unsigned)v.z; hi.y = (unsigned)v.w;
  *(u32x2*)p = lo;
  *(u32x2*)(p + 4) = hi;
}
__device__ __forceinline__ bf16x8 ld8(const short* p) {    // 8 bf16 from LDS as 2x b64
  union { bf16x8 v8; s16x4 h[2]; } u;
  u.h[0] = *(const s16x4*)p;
  u.h[1] = *(const s16x4*)(p + 4);
  return u.v8;
}
__device__ __forceinline__ float tanh_fast(float z) {
  float e = __expf(2.f * z);
  return 1.f - 2.f / (e + 1.f);
}

__device__ __forceinline__ void mfma_chunk(const short* sW, const short* sS,
                                           int wv, int l15, int quad, int c,
                                           f32x4& acc0, f32x4& acc1) {
  const short* Brow  = sW + (wv * 16 + l15) * WSTR + c * KC + quad * 8;
  const short* Arow0 = sS + l15 * SSTR + quad * 8;
  const short* Arow1 = Arow0 + 16 * SSTR;
#pragma unroll
  for (int ks = 0; ks < 8; ++ks) {
    bf16x8 bfr = ld8(Brow  + ks * 32);
    bf16x8 a0  = ld8(Arow0 + ks * 32);
    bf16x8 a1  = ld8(Arow1 + ks * 32);
    acc0 = __builtin_amdgcn_mfma_f32_16x16x32_bf16(a0, bfr, acc0, 0, 0, 0);
    acc1 = __builtin_amdgcn_mfma_f32_16x16x32_bf16(a1, bfr, acc1, 0, 0, 0);
  }
}

__global__ void __launch_bounds__(256, 1)
rnn_persistent(const float* __restrict__ x, const float* __restrict__ Whx,
               const float* __restrict__ Whh, const float* __restrict__ bh,
               const float* __restrict__ Wph, const float* __restrict__ bp,
               float* __restrict__ out, unsigned short* hbuf, int* flags)
{
  extern __shared__ short smem[];
  short* sW = smem;                 // [JT][WSTR] bf16 W_hh slice, persistent
  short* sS = smem + JT * WSTR;     // [BT][SSTR] bf16 h k-chunk stage (+ hS overlay)
  float* xb = (float*)(smem + JT * WSTR + BT * SSTR);  // [BT][XBSTR] x tile

  const int tid  = threadIdx.x;
  const int bg   = blockIdx.x & 15;
  const int jg   = blockIdx.x >> 4;
  const int lane = tid & 63;
  const int wv   = tid >> 6;          // wave = n-tile (16 cols each)
  const int l15  = lane & 15;
  const int quad = lane >> 4;

  // ---- stage W_hh[jg*64 .. +64)[0..1024) into LDS as bf16 ----
  {
    const int jr = tid >> 2;
    const int kq = tid & 3;
    const float* src = Whh + (jg * JT + jr) * HID + kq * 256;
    short* dst = sW + jr * WSTR + kq * 256;
#pragma unroll 4
    for (int i = 0; i < 64; ++i) {
      float4 f = *(const float4*)(src + i * 4);
      s16x4 h4;
      h4.x = (short)f2bf(f.x); h4.y = (short)f2bf(f.y);
      h4.z = (short)f2bf(f.z); h4.w = (short)f2bf(f.w);
      *(s16x4*)(dst + i * 4) = h4;
    }
  }

  const int j = jg * JT + wv * 16 + l15;       // per-lane output column
  const float whx = Whx[j];
  const float bhv = bh[j];

  // staging thread mapping: 64 B per thread per chunk
  const int sr  = tid >> 3;               // 0..31 stage row
  const int seg = tid & 7;                // 0..7

  int* myflags = flags + bg * 64;         // 16 flags, one 64B line per bg

  for (int t = 0; t < SEQ; ++t) {
    const unsigned short* hin = hbuf + ((t + 1) & 1) * HBUF_HALVES;
    unsigned short*      hout = hbuf + (t & 1) * HBUF_HALVES;

    // ---- x tile refill (every 32 steps): 32 rows x 32 steps into LDS ----
    if ((t & 31) == 0) {
      barrier_lgkm();                     // prior xb readers (and W-stage writes) done
      const int xr = tid >> 3;
      const int xc = (tid & 7) * 4;
      float4 xt = *(const float4*)(x + (bg * BT + xr) * SEQ + t + xc);
      xb[xr * XBSTR + xc + 0] = xt.x;
      xb[xr * XBSTR + xc + 1] = xt.y;
      xb[xr * XBSTR + xc + 2] = xt.z;
      xb[xr * XBSTR + xc + 3] = xt.w;
      __syncthreads();                    // tile visible (full drain, 8x total: cheap)
    }
    float xv0[4], xv1[4];
    {
      const int tc = t & 31;
#pragma unroll
      for (int rg = 0; rg < 4; ++rg) {
        xv0[rg] = xb[(quad * 4 + rg) * XBSTR + tc];
        xv1[rg] = xb[(16 + quad * 4 + rg) * XBSTR + tc];
      }
    }

    f32x4 acc0 = {0.f, 0.f, 0.f, 0.f};
    f32x4 acc1 = {0.f, 0.f, 0.f, 0.f};

    if (t > 0) {
      // acquire: wait for all 16 peers of this batch-group to finish step t-1
      if (tid < GJ) {
        while (load_flag(myflags + tid) < t) {}
      }
      // kill our CU's (possibly stale) L1 lines of hin; drained in-asm so the
      // barrier below orders it before every wave's staging loads.
      if (tid == 0) l1_inv_wait();
      __syncthreads();

      const char* lbase = (const char*)(hin + (bg * BT + sr) * HID) + seg * 16;
      short* sdst = sS + sr * SSTR + seg * 8;

      i32x4 a0, a1, a2, a3, b0, b1, b2, b3, c0, c1, c2, c3, d0, d1, d2, d3;
      issue4(lbase,        a0, a1, a2, a3);   // chunk 0
      issue4(lbase + 512,  b0, b1, b2, b3);   // chunk 1
      issue4(lbase + 1024, c0, c1, c2, c3);   // chunk 2
      issue4(lbase + 1536, d0, d1, d2, d3);   // chunk 3

      // chunk 0 (stage free: post-spin __syncthreads was the barrier)
      wait_vm12(a0, a1, a2, a3);
      wr16(sdst, a0); wr16(sdst + 64, a1); wr16(sdst + 128, a2); wr16(sdst + 192, a3);
      barrier_lgkm();
      mfma_chunk(sW, sS, wv, l15, quad, 0, acc0, acc1);

      // chunk 1
      barrier_lgkm();                          // all waves done reading chunk 0
      wait_vm8(b0, b1, b2, b3);
      wr16(sdst, b0); wr16(sdst + 64, b1); wr16(sdst + 128, b2); wr16(sdst + 192, b3);
      barrier_lgkm();
      mfma_chunk(sW, sS, wv, l15, quad, 1, acc0, acc1);

      // chunk 2
      barrier_lgkm();
      wait_vm4(c0, c1, c2, c3);
      wr16(sdst, c0); wr16(sdst + 64, c1); wr16(sdst + 128, c2); wr16(sdst + 192, c3);
      barrier_lgkm();
      mfma_chunk(sW, sS, wv, l15, quad, 2, acc0, acc1);

      // chunk 3
      barrier_lgkm();
      wait_vm0(d0, d1, d2, d3);
      wr16(sdst, d0); wr16(sdst + 64, d1); wr16(sdst + 128, d2); wr16(sdst + 192, d3);
      barrier_lgkm();
      mfma_chunk(sW, sS, wv, l15, quad, 3, acc0, acc1);
    }

    // ---- epilogue: h = tanh(acc + x*whx + bh), exchange via LDS, coalesced store ----
    barrier_lgkm();     // chunk-3 stage reads done everywhere (sS reused as hS)
    {
      short* hS = sS;   // [BT][HSTR] overlay
#pragma unroll
      for (int rg = 0; rg < 4; ++rg) {
        float z0 = acc0[rg] + xv0[rg] * whx + bhv;
        hS[(quad * 4 + rg) * HSTR + wv * 16 + l15] = (short)f2bf(tanh_fast(z0));
        float z1 = acc1[rg] + xv1[rg] * whx + bhv;
        hS[(16 + quad * 4 + rg) * HSTR + wv * 16 + l15] = (short)f2bf(tanh_fast(z1));
      }
    }
    barrier_lgkm();
    {
      const short* hsrc = sS + sr * HSTR + seg * 8;
      u32x2 lo = *(const u32x2*)(hsrc);
      u32x2 hi = *(const u32x2*)(hsrc + 4);
      i32x4 sv; sv.x = (int)lo.x; sv.y = (int)lo.y; sv.z = (int)hi.x; sv.w = (int)hi.y;
      unsigned short* dst = hout + (bg * BT + sr) * HID + jg * JT + seg * 8;
      store16(dst, sv);
    }
    waitcnt0();          // this thread's 4KB-coalesced store retired (L2+MALL)
    barrier_lgkm();      // all threads retired before the flag release
    if (tid == 0) store_flag(myflags + jg, t + 1);
  }

  // ---- output head: out[b, jg*8+cc] = h_last . W_ph[c] + b_p ----
  if (tid < GJ) {
    while (load_flag(myflags + tid) < SEQ) {}
  }
  if (tid == 0) l1_inv_wait();   // h_last loads below are plain/cacheable
  __syncthreads();

  const unsigned short* hlast = hbuf + ((SEQ - 1) & 1) * HBUF_HALVES;
  const int cc = tid & 7;
  const int cg = jg * 8 + cc;
  const int hr = tid >> 3;
  float acc = 0.f;
  const char* lbase = (const char*)(hlast + (bg * BT + sr) * HID) + seg * 16;
  short* sdst = sS + sr * SSTR + seg * 8;
  for (int c = 0; c < 4; ++c) {
    __syncthreads();
    i32x4 p0, p1, p2, p3;
    issue4(lbase + c * 512, p0, p1, p2, p3);
    waitcnt0();
    wr16(sdst, p0); wr16(sdst + 64, p1); wr16(sdst + 128, p2); wr16(sdst + 192, p3);
    __syncthreads();
    const float* wp = Wph + cg * HID + c * KC;
    const short* hs = sS + hr * SSTR;
#pragma unroll 8
    for (int k4 = 0; k4 < 64; ++k4) {
      float4 w  = *(const float4*)(wp + k4 * 4);
      s16x4 hv  = *(const s16x4*)(hs + k4 * 4);
      acc += b2f(hv.x) * w.x + b2f(hv.y) * w.y + b2f(hv.z) * w.z + b2f(hv.w) * w.w;
    }
  }
  out[(bg * BT + hr) * CLS + cg] = acc + bp[cg];
}

extern "C" void kernel_launch(void* const* d_in, const int* in_sizes, int n_in,
                              void* d_out, int out_size, void* d_ws, size_t ws_size,
                              hipStream_t stream) {
  const float* x   = (const float*)d_in[0];
  const float* Whx = (const float*)d_in[1];
  const float* Whh = (const float*)d_in[2];
  const float* bh  = (const float*)d_in[3];
  const float* Wph = (const float*)d_in[4];
  const float* bp  = (const float*)d_in[5];
  float* out = (float*)d_out;

  unsigned short* hbuf = (unsigned short*)d_ws;
  int* flags = (int*)((char*)d_ws + (size_t)2 * HBUF_HALVES * 2);

  hipFuncSetAttribute(reinterpret_cast<const void*>(rnn_persistent),
                      hipFuncAttributeMaxDynamicSharedMemorySize, SMEM_BYTES);

  rnn_persistent<<<dim3(GB * GJ), dim3(256), SMEM_BYTES, stream>>>(
      x, Whx, Whh, bh, Wph, bp, out, hbuf, flags);
}

// Round 6
// 1028.358 us; speedup vs baseline: 1.4371x; 1.0769x over previous
//
#include <hip/hip_runtime.h>
#include <stdint.h>

// Persistent-kernel RNN: 256 wgs (1/CU), W_hh bf16 resident in LDS (16 j-slices),
// batch split 16 ways; h exchanged via MALL with sc0 sc1 + per-group flags (R2
// protocol — best verified: every protocol variant (sentinel R5, sc1-only R6,
// L2-cached+L1-inv R7) landed within +-15%, so exchange RTT is not the lever).
// R8: LDS-READ DIET. Step budget showed 768 ds_read_b64/wg/step (384 KB, ~4600
// cy at 85 B/cy) — ~45% of the step — caused by 2x1 wave blocking (3 b64 per
// MFMA). Now each wave computes a 2x2 tile block (4 accs: A-frag and B-frag
// each feed 2 MFMAs -> 2 b64/MFMA), with wave pairs (w, w+2) splitting each
// chunk's k-range (ks 0-3 vs 4-7) so all 4 waves work on every staged chunk and
// the staging/barrier/vmcnt ladder is UNCHANGED. Partial accs of k-partners are
// merged via an 8 KB LDS scratch (+1 barrier) before tanh.
// LDS reads: 768 -> 512 b64 per wg per step (-33%).

#define BATCH 512
#define SEQ   256
#define HID   1024
#define CLS   128

#define GB 16          // batch groups
#define GJ 16          // hidden slices
#define BT 32          // batch rows per wg
#define JT 64          // hidden cols per wg
#define KC 256         // k-chunk per stage buffer fill
#define WSTR 1028      // W LDS row stride (halves): 2-way banks, 8B aligned
#define SSTR 260       // stage row stride (halves)
#define HSTR 68        // h-store exchange row stride (halves)
#define SMEM_BYTES ((JT * WSTR + BT * SSTR) * 2)   // 148224 B
#define HBUF_HALVES (BATCH * HID)                  // 1 MB per buffer
#define RED_OFF 2176   // halves: acc-reduction scratch at sS+4352 B (above hS)

typedef __attribute__((ext_vector_type(8))) short  bf16x8;
typedef __attribute__((ext_vector_type(4))) short  s16x4;
typedef __attribute__((ext_vector_type(4))) float  f32x4;
typedef __attribute__((ext_vector_type(4))) int    i32x4;
typedef __attribute__((ext_vector_type(2))) unsigned int u32x2;

__device__ __forceinline__ unsigned short f2bf(float f) {
  unsigned int u = __float_as_uint(f);
  u = (u + 0x7FFFu + ((u >> 16) & 1u)) >> 16;   // RNE
  return (unsigned short)u;
}
__device__ __forceinline__ float b2f(short h) {
  return __uint_as_float(((unsigned int)(unsigned short)h) << 16);
}

// ---- device-coherent (MALL) accesses ----
__device__ __forceinline__ void store_flag(int* p, int v) {
  asm volatile("global_store_dword %0, %1, off sc0 sc1" :: "v"(p), "v"(v) : "memory");
}
__device__ __forceinline__ int load_flag(const int* p) {
  int v;
  asm volatile("global_load_dword %0, %1, off sc0 sc1\n\t"
               "s_waitcnt vmcnt(0)" : "=v"(v) : "v"(p) : "memory");
  return v;
}
__device__ __forceinline__ void store16(void* p, i32x4 v) {
  asm volatile("global_store_dwordx4 %0, %1, off sc0 sc1" :: "v"(p), "v"(v) : "memory");
}
__device__ __forceinline__ void waitcnt0() {
  asm volatile("s_waitcnt vmcnt(0)" ::: "memory");
}
// raw workgroup barrier: drains LDS ops only — global loads stay in flight
__device__ __forceinline__ void barrier_lgkm() {
  asm volatile("s_waitcnt lgkmcnt(0)\n\ts_barrier" ::: "memory");
}
// issue 4x dwordx4 coherent loads (64 B/thread), no wait
__device__ __forceinline__ void issue4(const void* p, i32x4& a, i32x4& b, i32x4& c, i32x4& d) {
  asm volatile(
    "global_load_dwordx4 %0, %4, off sc0 sc1\n\t"
    "global_load_dwordx4 %1, %4, off offset:128 sc0 sc1\n\t"
    "global_load_dwordx4 %2, %4, off offset:256 sc0 sc1\n\t"
    "global_load_dwordx4 %3, %4, off offset:384 sc0 sc1"
    : "=&v"(a), "=&v"(b), "=&v"(c), "=&v"(d)
    : "v"(p) : "memory");
}
// counted waits, tying the chunk's registers so LDS writes can't be hoisted
#define DEF_WAIT(NAME, N) \
__device__ __forceinline__ void NAME(i32x4& a, i32x4& b, i32x4& c, i32x4& d) { \
  asm volatile("s_waitcnt vmcnt(" #N ")" : "+v"(a), "+v"(b), "+v"(c), "+v"(d) :: "memory"); \
}
DEF_WAIT(wait_vm12, 12)
DEF_WAIT(wait_vm8, 8)
DEF_WAIT(wait_vm4, 4)
DEF_WAIT(wait_vm0, 0)

__device__ __forceinline__ void wr16(short* p, i32x4 v) {  // 16 B to LDS as 2x b64
  u32x2 lo, hi;
  lo.x = (unsigned)v.x; lo.y = (unsigned)v.y;
  hi.x = (unsigned)v.z; hi.y = (unsigned)v.w;
  *(u32x2*)p = lo;
  *(u32x2*)(p + 4) = hi;
}
__device__ __forceinline__ bf16x8 ld8(const short* p) {    // 8 bf16 from LDS as 2x b64
  union { bf16x8 v8; s16x4 h[2]; } u;
  u.h[0] = *(const s16x4*)p;
  u.h[1] = *(const s16x4*)(p + 4);
  return u.v8;
}
__device__ __forceinline__ float tanh_fast(float z) {
  float e = __expf(2.f * z);
  return 1.f - 2.f / (e + 1.f);
}

// 2x2 block, k-half per wave pair: 16 ld8 (32 b64) for 16 MFMAs per chunk.
__device__ __forceinline__ void mfma_chunk22(const short* sW, const short* sS,
                                             int cp, int kh, int l15, int quad, int c,
                                             f32x4& a00, f32x4& a01,
                                             f32x4& a10, f32x4& a11) {
  const short* B0  = sW + (cp * 32 + l15) * WSTR + c * KC + kh * 128 + quad * 8;
  const short* B1  = B0 + 16 * WSTR;
  const short* Ar0 = sS + l15 * SSTR + kh * 128 + quad * 8;
  const short* Ar1 = Ar0 + 16 * SSTR;
#pragma unroll
  for (int i = 0; i < 4; ++i) {
    bf16x8 b0 = ld8(B0  + i * 32);
    bf16x8 b1 = ld8(B1  + i * 32);
    bf16x8 a0 = ld8(Ar0 + i * 32);
    bf16x8 a1 = ld8(Ar1 + i * 32);
    a00 = __builtin_amdgcn_mfma_f32_16x16x32_bf16(a0, b0, a00, 0, 0, 0);
    a10 = __builtin_amdgcn_mfma_f32_16x16x32_bf16(a1, b0, a10, 0, 0, 0);
    a01 = __builtin_amdgcn_mfma_f32_16x16x32_bf16(a0, b1, a01, 0, 0, 0);
    a11 = __builtin_amdgcn_mfma_f32_16x16x32_bf16(a1, b1, a11, 0, 0, 0);
  }
}

__global__ void __launch_bounds__(256, 1)
rnn_persistent(const float* __restrict__ x, const float* __restrict__ Whx,
               const float* __restrict__ Whh, const float* __restrict__ bh,
               const float* __restrict__ Wph, const float* __restrict__ bp,
               float* __restrict__ out, unsigned short* hbuf, int* flags)
{
  extern __shared__ short smem[];
  short* sW = smem;                 // [JT][WSTR] bf16 W_hh slice, persistent
  short* sS = smem + JT * WSTR;     // [BT][SSTR] bf16 h k-chunk stage (+ hS/red overlay)

  const int tid  = threadIdx.x;
  const int bg   = blockIdx.x & 15;
  const int jg   = blockIdx.x >> 4;
  const int lane = tid & 63;
  const int wv   = tid >> 6;
  const int l15  = lane & 15;
  const int quad = lane >> 4;
  const int cp   = wv & 1;          // col-pair: this wave's cols = cp*32 .. +32
  const int kh   = wv >> 1;         // k-half within each chunk: ks = kh*4 .. +4

  // ---- stage W_hh[jg*64 .. +64)[0..1024) into LDS as bf16 ----
  {
    const int jr = tid >> 2;
    const int kq = tid & 3;
    const float* src = Whh + (jg * JT + jr) * HID + kq * 256;
    short* dst = sW + jr * WSTR + kq * 256;
#pragma unroll 4
    for (int i = 0; i < 64; ++i) {
      float4 f = *(const float4*)(src + i * 4);
      s16x4 h4;
      h4.x = (short)f2bf(f.x); h4.y = (short)f2bf(f.y);
      h4.z = (short)f2bf(f.z); h4.w = (short)f2bf(f.w);
      *(s16x4*)(dst + i * 4) = h4;
    }
  }

  // per-lane output columns (two tiles: ct=0,1 at cp*32 + ct*16 + l15)
  const int j0 = jg * JT + cp * 32 + l15;
  const int j1 = j0 + 16;
  const float whx0 = Whx[j0], whx1 = Whx[j1];
  const float bhv0 = bh[j0],  bhv1 = bh[j1];
  const int grow0 = bg * BT + quad * 4;        // batch row base (row-block 0)

  // staging thread mapping: 64 B per thread per chunk
  const int sr  = tid >> 3;               // 0..31 stage row
  const int seg = tid & 7;                // 0..7

  int* myflags = flags + bg * 64;         // 16 flags, one 64B line per bg

  for (int t = 0; t < SEQ; ++t) {
    const unsigned short* hin = hbuf + ((t + 1) & 1) * HBUF_HALVES;
    unsigned short*      hout = hbuf + (t & 1) * HBUF_HALVES;

    f32x4 acc00 = {0.f, 0.f, 0.f, 0.f};
    f32x4 acc01 = {0.f, 0.f, 0.f, 0.f};
    f32x4 acc10 = {0.f, 0.f, 0.f, 0.f};
    f32x4 acc11 = {0.f, 0.f, 0.f, 0.f};

    // x for this step — issued before the spin, drained by the spin/syncthreads
    float xv0[4], xv1[4];
    {
      const float* xp = x + grow0 * SEQ + t;
#pragma unroll
      for (int rg = 0; rg < 4; ++rg) {
        xv0[rg] = xp[rg * SEQ];
        xv1[rg] = xp[(16 + rg) * SEQ];
      }
    }

    if (t > 0) {
      // wait for all 16 peers of this batch-group to finish step t-1
      if (tid < GJ) {
        while (load_flag(myflags + tid) < t) {}
      }
      __syncthreads();   // full drain: vmcnt==0 entering the issue window

      const char* lbase = (const char*)(hin + (bg * BT + sr) * HID) + seg * 16;
      short* sdst = sS + sr * SSTR + seg * 8;

      i32x4 a0, a1, a2, a3, b0, b1, b2, b3, c0, c1, c2, c3, d0, d1, d2, d3;
      issue4(lbase,        a0, a1, a2, a3);   // chunk 0
      issue4(lbase + 512,  b0, b1, b2, b3);   // chunk 1
      issue4(lbase + 1024, c0, c1, c2, c3);   // chunk 2
      issue4(lbase + 1536, d0, d1, d2, d3);   // chunk 3

      // chunk 0 (stage free: post-spin __syncthreads was the barrier)
      wait_vm12(a0, a1, a2, a3);
      wr16(sdst, a0); wr16(sdst + 64, a1); wr16(sdst + 128, a2); wr16(sdst + 192, a3);
      barrier_lgkm();
      mfma_chunk22(sW, sS, cp, kh, l15, quad, 0, acc00, acc01, acc10, acc11);

      // chunk 1
      barrier_lgkm();                          // all waves done reading chunk 0
      wait_vm8(b0, b1, b2, b3);
      wr16(sdst, b0); wr16(sdst + 64, b1); wr16(sdst + 128, b2); wr16(sdst + 192, b3);
      barrier_lgkm();
      mfma_chunk22(sW, sS, cp, kh, l15, quad, 1, acc00, acc01, acc10, acc11);

      // chunk 2
      barrier_lgkm();
      wait_vm4(c0, c1, c2, c3);
      wr16(sdst, c0); wr16(sdst + 64, c1); wr16(sdst + 128, c2); wr16(sdst + 192, c3);
      barrier_lgkm();
      mfma_chunk22(sW, sS, cp, kh, l15, quad, 2, acc00, acc01, acc10, acc11);

      // chunk 3
      barrier_lgkm();
      wait_vm0(d0, d1, d2, d3);
      wr16(sdst, d0); wr16(sdst + 64, d1); wr16(sdst + 128, d2); wr16(sdst + 192, d3);
      barrier_lgkm();
      mfma_chunk22(sW, sS, cp, kh, l15, quad, 3, acc00, acc01, acc10, acc11);
    }

    // ---- k-pair reduction: wave kh finishes row-block kh; partner = wv^2 ----
    barrier_lgkm();     // chunk-3 stage reads done everywhere (sS reusable)
    {
      // write the two accs this wave does NOT finish (the other row-block)
      float* red = (float*)(sS + RED_OFF);
      f32x4 w0 = kh ? acc00 : acc10;
      f32x4 w1 = kh ? acc01 : acc11;
      *(f32x4*)(red + tid * 8)     = w0;
      *(f32x4*)(red + tid * 8 + 4) = w1;
    }
    barrier_lgkm();
    {
      const float* red = (const float*)(sS + RED_OFF);
      const int ptid = tid ^ 128;           // partner wave wv^2, same lane
      f32x4 r0 = *(const f32x4*)(red + ptid * 8);
      f32x4 r1 = *(const f32x4*)(red + ptid * 8 + 4);
      f32x4 f0 = (kh ? acc10 : acc00) + r0;
      f32x4 f1 = (kh ? acc11 : acc01) + r1;

      // h = tanh(acc + x*whx + bh) into hS (disjoint from red: hS < 4352 B)
      short* hS = sS;   // [BT][HSTR] overlay
      const int rbase = kh * 16 + quad * 4;
#pragma unroll
      for (int rg = 0; rg < 4; ++rg) {
        float xr = kh ? xv1[rg] : xv0[rg];
        float z0 = f0[rg] + xr * whx0 + bhv0;
        hS[(rbase + rg) * HSTR + cp * 32 + l15] = (short)f2bf(tanh_fast(z0));
        float z1 = f1[rg] + xr * whx1 + bhv1;
        hS[(rbase + rg) * HSTR + cp * 32 + 16 + l15] = (short)f2bf(tanh_fast(z1));
      }
    }
    barrier_lgkm();
    {
      const short* hsrc = sS + sr * HSTR + seg * 8;
      u32x2 lo = *(const u32x2*)(hsrc);
      u32x2 hi = *(const u32x2*)(hsrc + 4);
      i32x4 sv; sv.x = (int)lo.x; sv.y = (int)lo.y; sv.z = (int)hi.x; sv.w = (int)hi.y;
      unsigned short* dst = hout + (bg * BT + sr) * HID + jg * JT + seg * 8;
      store16(dst, sv);
    }
    waitcnt0();          // this thread's 4KB-coalesced store retired at MALL
    barrier_lgkm();      // all threads retired before the flag release
    if (tid == 0) store_flag(myflags + jg, t + 1);
  }

  // ---- output head: out[b, jg*8+cc] = h_last . W_ph[c] + b_p ----
  if (tid < GJ) {
    while (load_flag(myflags + tid) < SEQ) {}
  }
  __syncthreads();

  const unsigned short* hlast = hbuf + ((SEQ - 1) & 1) * HBUF_HALVES;
  const int cc = tid & 7;
  const int cg = jg * 8 + cc;
  const int hr = tid >> 3;
  float acc = 0.f;
  const char* lbase = (const char*)(hlast + (bg * BT + sr) * HID) + seg * 16;
  short* sdst = sS + sr * SSTR + seg * 8;
  for (int c = 0; c < 4; ++c) {
    __syncthreads();
    i32x4 p0, p1, p2, p3;
    issue4(lbase + c * 512, p0, p1, p2, p3);
    waitcnt0();
    wr16(sdst, p0); wr16(sdst + 64, p1); wr16(sdst + 128, p2); wr16(sdst + 192, p3);
    __syncthreads();
    const float* wp = Wph + cg * HID + c * KC;
    const short* hs = sS + hr * SSTR;
#pragma unroll 8
    for (int k4 = 0; k4 < 64; ++k4) {
      float4 w  = *(const float4*)(wp + k4 * 4);
      s16x4 hv  = *(const s16x4*)(hs + k4 * 4);
      acc += b2f(hv.x) * w.x + b2f(hv.y) * w.y + b2f(hv.z) * w.z + b2f(hv.w) * w.w;
    }
  }
  out[(bg * BT + hr) * CLS + cg] = acc + bp[cg];
}

extern "C" void kernel_launch(void* const* d_in, const int* in_sizes, int n_in,
                              void* d_out, int out_size, void* d_ws, size_t ws_size,
                              hipStream_t stream) {
  const float* x   = (const float*)d_in[0];
  const float* Whx = (const float*)d_in[1];
  const float* Whh = (const float*)d_in[2];
  const float* bh  = (const float*)d_in[3];
  const float* Wph = (const float*)d_in[4];
  const float* bp  = (const float*)d_in[5];
  float* out = (float*)d_out;

  unsigned short* hbuf = (unsigned short*)d_ws;
  int* flags = (int*)((char*)d_ws + (size_t)2 * HBUF_HALVES * 2);

  hipFuncSetAttribute(reinterpret_cast<const void*>(rnn_persistent),
                      hipFuncAttributeMaxDynamicSharedMemorySize, SMEM_BYTES);

  rnn_persistent<<<dim3(GB * GJ), dim3(256), SMEM_BYTES, stream>>>(
      x, Whx, Whh, bh, Wph, bp, out, hbuf, flags);
}